// Round 1
// baseline (341.433 us; speedup 1.0000x reference)
//
#include <hip/hip_runtime.h>

// SSM4D: causal depthwise conv1d, B=16, C=1024, T=3000, K=24, fp32.
// y[b,c,t] = sum_{d=0..23} w[c][d] * x[b,c,t-d],  w[c][d] = kern[c][K-1-d]
// kern[c][k] = beta[c] * exp(log(max(alpha[c],1e-6))*k) * cos4(theta[c]*k)
//
// R3: coalesced loads. R2 (OPT=8, per-lane-contiguous 128B windows) made every
// global_load_dwordx4 touch 64 distinct cache lines (lane stride 128B) -> TA
// transaction-bound (~64 line xacts/instr, ~80us floor). Now OPT=4: lane i owns
// the float4 at t0+4*i, lane stride 16B -> each of the 7 window loads is one
// contiguous 1KB wave transaction (L1 absorbs the 7x overlap). HBM traffic
// unchanged (~197MB read + ~197MB write -> ~62us roofline).

#define KSZ   24
#define T_LEN 3000
#define C_CH  1024
#define B_N   16
#define OPT   4            // outputs per thread (one float4)
#define TPB   256
#define TILE  (TPB * OPT)  // 1024

__device__ __forceinline__ float cos_approx(float v) {
    float v2 = v * v;
    return 1.0f - 0.5f * v2 + (v2 * v2) * (1.0f / 24.0f);
}

__global__ void ssm4d_weights(const float* __restrict__ alpha,
                              const float* __restrict__ beta,
                              const float* __restrict__ theta,
                              float* __restrict__ w) {
    const int i = blockIdx.x * blockDim.x + threadIdx.x;   // i = c*24 + d
    if (i >= C_CH * KSZ) return;
    const int c = i / KSZ;
    const int d = i - c * KSZ;
    const int k = (KSZ - 1) - d;                           // flip for causal FIR
    const float a   = fmaxf(alpha[c], 1e-6f);
    const float dec = expf(logf(a) * (float)k);
    w[i] = beta[c] * dec * cos_approx(theta[c] * (float)k);
}

__global__ __launch_bounds__(TPB) void ssm4d_conv(
        const float* __restrict__ x,
        const float* __restrict__ w,
        float* __restrict__ y) {
    const int row  = blockIdx.y;                 // b*C + c
    const int c    = row & (C_CH - 1);
    const long base = (long)row * T_LEN;
    const int t    = blockIdx.x * TILE + threadIdx.x * OPT;  // first output
    if (t >= T_LEN) return;                      // tail block: t>=3000 idle
                                                 // (3000%4==0 -> no partial float4)

    // 24 weights: block-uniform addresses -> L1/L2 broadcast, 6x float4
    float wr[KSZ];
    const float4* wp = (const float4*)(w + c * KSZ);
#pragma unroll
    for (int q = 0; q < KSZ / 4; ++q) {
        float4 v = wp[q];
        wr[4 * q + 0] = v.x; wr[4 * q + 1] = v.y;
        wr[4 * q + 2] = v.z; wr[4 * q + 3] = v.w;
    }

    // window win[p] = x[t - 24 + p], p = 0..27 (win[0] unused)
    // 7 float4 loads, lane stride 16B: each is one contiguous 1KB wave xact;
    // consecutive q loads overlap 6/7 in address range -> L1 hits.
    float win[KSZ + OPT];
    if (t >= KSZ) {
        const float4* xp = (const float4*)(x + base + t - KSZ);
#pragma unroll
        for (int q = 0; q < (KSZ + OPT) / 4; ++q) {
            float4 v = xp[q];
            win[4 * q + 0] = v.x; win[4 * q + 1] = v.y;
            win[4 * q + 2] = v.z; win[4 * q + 3] = v.w;
        }
    } else {
        // only threads 0..5 of blockIdx.x==0: causal zero-pad
#pragma unroll
        for (int p = 0; p < KSZ + OPT; ++p) {
            const int idx = t - KSZ + p;
            win[p] = (idx >= 0) ? x[base + idx] : 0.0f;
        }
    }

    float acc[OPT];
#pragma unroll
    for (int m = 0; m < OPT; ++m) acc[m] = 0.0f;
#pragma unroll
    for (int d = 0; d < KSZ; ++d) {
#pragma unroll
        for (int m = 0; m < OPT; ++m)
            acc[m] = fmaf(wr[d], win[KSZ + m - d], acc[m]);  // y[t+m] += w[d]*x[t+m-d]
    }

    *(float4*)(y + base + t) = make_float4(acc[0], acc[1], acc[2], acc[3]);
}

extern "C" void kernel_launch(void* const* d_in, const int* in_sizes, int n_in,
                              void* d_out, int out_size, void* d_ws, size_t ws_size,
                              hipStream_t stream) {
    const float* x     = (const float*)d_in[0];
    const float* alpha = (const float*)d_in[1];
    const float* beta  = (const float*)d_in[2];
    const float* theta = (const float*)d_in[3];
    float* y = (float*)d_out;
    float* w = (float*)d_ws;                     // 1024*24 floats = 96 KB

    ssm4d_weights<<<(C_CH * KSZ + 255) / 256, 256, 0, stream>>>(alpha, beta, theta, w);

    dim3 grid((T_LEN + TILE - 1) / TILE, B_N * C_CH);   // (3, 16384)
    ssm4d_conv<<<grid, TPB, 0, stream>>>(x, w, y);
}